// Round 1
// baseline (707.152 us; speedup 1.0000x reference)
//
#include <hip/hip_runtime.h>
#include <math.h>

#define CCH 512
#define F1 25088      // 512*49
#define FC 4096
#define NCLS 1000
#define OW 224

// ws float offsets
#define WS_DT 0                         // [4096][512] Dt[j][i]
#define WS_MP (WS_DT + FC*CCH)          // 25088
#define WS_H1PRE (WS_MP + F1)           // 4096
#define WS_H1 (WS_H1PRE + FC)           // 4096
#define WS_H2 (WS_H1 + FC)              // 4096
#define WS_LOGITS (WS_H2 + FC)          // 1000
#define WS_CLSBASE (WS_LOGITS + NCLS)   // 2: [0]=cls, [1]=base
#define WS_LOGPART (WS_CLSBASE + 2)     // [64][512]
#define WS_MINMAX (WS_LOGPART + 64*CCH) // 2 ints
#define WS_WEIGHTED (WS_MINMAX + 2)     // 196

// -------- maxpool 2x2 (+ init minmax) --------
__global__ void k_maxpool(const float* __restrict__ act, float* __restrict__ ws) {
    int t = threadIdx.x;
    if (blockIdx.x == 0) {
        if (t == 0) ((int*)(ws + WS_MINMAX))[0] = 0x7F800000; // +inf
        if (t == 1) ((int*)(ws + WS_MINMAX))[1] = 0;          // 0.0f
    }
    int idx = blockIdx.x * 256 + t;
    if (idx >= CCH * 49) return;
    int c = idx / 49, r = idx % 49, y = r / 7, x = r % 7;
    const float* a = act + c * 196 + (2 * y) * 14 + 2 * x;
    float m = fmaxf(fmaxf(a[0], a[1]), fmaxf(a[14], a[15]));
    ws[WS_MP + idx] = m;
}

// -------- per-channel layer-1 partials: Dt[j][i] = dot(W1[j, i*49: ], mp[i*49: ]) --------
__global__ void k_phi(const float* __restrict__ W1, const float* __restrict__ mp,
                      float* __restrict__ Dt) {
    int j = blockIdx.x;       // 0..4095
    int i = threadIdx.x;      // 0..511 channel
    const float* w = W1 + (size_t)j * F1 + i * 49;
    const float* m = mp + i * 49;
    float s = 0.f;
    for (int k = 0; k < 49; ++k) s = fmaf(w[k], m[k], s);
    Dt[(size_t)j * CCH + i] = s;
}

// -------- h1pre[j] = b1[j] + rowsum(Dt[j]); h1 = relu --------
__global__ void k_h1(const float* __restrict__ Dt, const float* __restrict__ b1,
                     float* __restrict__ h1pre, float* __restrict__ h1) {
    int j = blockIdx.x, t = threadIdx.x; // 64 threads
    const float* row = Dt + (size_t)j * CCH;
    float s = 0.f;
    for (int i = t; i < CCH; i += 64) s += row[i];
    for (int off = 32; off > 0; off >>= 1) s += __shfl_down(s, off, 64);
    if (t == 0) { float v = b1[j] + s; h1pre[j] = v; h1[j] = fmaxf(v, 0.f); }
}

// -------- generic GEMV: out[j] = (relu?)(bias[j] + dot(M[j,:K], v)) --------
template <int K, bool RELU>
__global__ void k_gemv(const float* __restrict__ M, const float* __restrict__ v,
                       const float* __restrict__ bias, float* __restrict__ out) {
    int j = blockIdx.x, t = threadIdx.x; // 256 threads
    const float* row = M + (size_t)j * K;
    float s = 0.f;
    for (int k = t; k < K; k += 256) s = fmaf(row[k], v[k], s);
    __shared__ float red[256];
    red[t] = s; __syncthreads();
    if (t < 128) red[t] += red[t + 128]; __syncthreads();
    if (t < 64)  red[t] += red[t + 64];  __syncthreads();
    if (t < 64) {
        float x = red[t];
        for (int off = 32; off > 0; off >>= 1) x += __shfl_down(x, off, 64);
        if (t == 0) { float r = bias[j] + x; out[j] = RELU ? fmaxf(r, 0.f) : r; }
    }
}

// -------- argmax over logits (first max) --------
__global__ void k_argmax(const float* __restrict__ logits, float* __restrict__ clsbase,
                         float* __restrict__ dout_cls) {
    int t = threadIdx.x;
    float best = -INFINITY; int bi = NCLS;
    for (int n = t; n < NCLS; n += 256) {
        float v = logits[n];
        if (v > best || (v == best && n < bi)) { best = v; bi = n; }
    }
    __shared__ float bv[256]; __shared__ int bidx[256];
    bv[t] = best; bidx[t] = bi; __syncthreads();
    for (int o = 128; o > 0; o >>= 1) {
        if (t < o) {
            float v2 = bv[t + o]; int i2 = bidx[t + o];
            if (v2 > bv[t] || (v2 == bv[t] && i2 < bidx[t])) { bv[t] = v2; bidx[t] = i2; }
        }
        __syncthreads();
    }
    if (t == 0) { clsbase[0] = (float)bidx[0]; clsbase[1] = bv[0]; *dout_cls = (float)bidx[0]; }
}

// -------- batched ablation layer-2 GEMM + fused W3-row dot --------
// A[i][k] = relu(h1pre[k] - Dt[k][i]),  H2pre = A @ W2^T + b2, fused:
// logit_part[nj][i] = sum_{j2 in tile nj} relu(H2pre[i][j2]) * W3[cls][j2]
__global__ __launch_bounds__(256) void k_gemm_abl(
    const float* __restrict__ Dt, const float* __restrict__ h1pre,
    const float* __restrict__ W2, const float* __restrict__ b2,
    const float* __restrict__ W3, const float* __restrict__ clsbase,
    float* __restrict__ logit_part) {
    int mi = blockIdx.x;  // 8 tiles of i (512/64)
    int nj = blockIdx.y;  // 64 tiles of j2 (4096/64)
    int t = threadIdx.x;
    int tx = t & 15, ty = t >> 4;
    int i0 = mi * 64, j0 = nj * 64;

    __shared__ float As[16][64];
    __shared__ float Bs[16][65];
    float acc[4][4] = {};

    for (int k0 = 0; k0 < FC; k0 += 16) {
        #pragma unroll
        for (int r = 0; r < 4; ++r) {
            int e = t + 256 * r; int kk = e >> 6, ii = e & 63;
            float hp = h1pre[k0 + kk];
            float d = Dt[(size_t)(k0 + kk) * CCH + i0 + ii];
            As[kk][ii] = fmaxf(hp - d, 0.f);
        }
        {
            int jj = t >> 2, kks = (t & 3) * 4;
            const float4 wv = *(const float4*)(W2 + (size_t)(j0 + jj) * FC + k0 + kks);
            Bs[kks + 0][jj] = wv.x; Bs[kks + 1][jj] = wv.y;
            Bs[kks + 2][jj] = wv.z; Bs[kks + 3][jj] = wv.w;
        }
        __syncthreads();
        #pragma unroll
        for (int kk = 0; kk < 16; ++kk) {
            float4 a4 = *(const float4*)&As[kk][tx * 4];
            float av[4] = {a4.x, a4.y, a4.z, a4.w};
            float bv[4] = {Bs[kk][ty * 4 + 0], Bs[kk][ty * 4 + 1],
                           Bs[kk][ty * 4 + 2], Bs[kk][ty * 4 + 3]};
            #pragma unroll
            for (int a = 0; a < 4; ++a)
                #pragma unroll
                for (int b = 0; b < 4; ++b)
                    acc[a][b] = fmaf(av[a], bv[b], acc[a][b]);
        }
        __syncthreads();
    }

    int cls = (int)clsbase[0];
    const float* w3r = W3 + (size_t)cls * FC;
    float part[4] = {0.f, 0.f, 0.f, 0.f};
    #pragma unroll
    for (int b = 0; b < 4; ++b) {
        int j2 = j0 + ty * 4 + b;
        float bb = b2[j2], w3 = w3r[j2];
        #pragma unroll
        for (int a = 0; a < 4; ++a) {
            float v = fmaxf(acc[a][b] + bb, 0.f);
            part[a] = fmaf(v, w3, part[a]);
        }
    }
    __shared__ float red[16][68];
    #pragma unroll
    for (int a = 0; a < 4; ++a) red[ty][tx * 4 + a] = part[a];
    __syncthreads();
    if (t < 64) {
        float s = 0.f;
        #pragma unroll
        for (int q = 0; q < 16; ++q) s += red[q][t];
        logit_part[nj * CCH + i0 + t] = s;
    }
}

// -------- alpha + weighted 14x14 map --------
__global__ void k_weighted(const float* __restrict__ logit_part, const float* __restrict__ b3,
                           const float* __restrict__ clsbase, const float* __restrict__ act,
                           float* __restrict__ weighted) {
    __shared__ float sA[CCH];
    int t = threadIdx.x;
    int cls = (int)clsbase[0]; float base = clsbase[1];
    float b3c = b3[cls];
    for (int i = t; i < CCH; i += 256) {
        float s = 0.f;
        for (int q = 0; q < 64; ++q) s += logit_part[q * CCH + i];
        float logit_i = s + b3c;
        sA[i] = (base - logit_i) / base;
    }
    __syncthreads();
    for (int p = t; p < 196; p += 256) {
        float s = 0.f;
        for (int i = 0; i < CCH; ++i) s = fmaf(sA[i], act[i * 196 + p], s);
        weighted[p] = s;
    }
}

// -------- bilinear 14->224 + relu + min/max --------
__global__ void k_resize(const float* __restrict__ weighted, float* __restrict__ out,
                         int* __restrict__ minmax) {
    __shared__ float sW[196];
    int t = threadIdx.x;
    if (t < 196) sW[t] = weighted[t];
    __syncthreads();
    int pix = blockIdx.x * 256 + t; // 196*256 = 50176
    int y = pix / OW, x = pix % OW;
    float uy = (y + 0.5f) * 0.0625f - 0.5f;
    float ux = (x + 0.5f) * 0.0625f - 0.5f;
    float y0f = floorf(uy), x0f = floorf(ux);
    float fy = uy - y0f, fx = ux - x0f;
    int y0 = (int)y0f, x0 = (int)x0f;
    int y0c = min(max(y0, 0), 13), y1c = min(max(y0 + 1, 0), 13);
    int x0c = min(max(x0, 0), 13), x1c = min(max(x0 + 1, 0), 13);
    float v00 = sW[y0c * 14 + x0c], v01 = sW[y0c * 14 + x1c];
    float v10 = sW[y1c * 14 + x0c], v11 = sW[y1c * 14 + x1c];
    float v0 = v00 + (v01 - v00) * fx;
    float v1 = v10 + (v11 - v10) * fx;
    float v = v0 + (v1 - v0) * fy;
    float f = fmaxf(v, 0.f);
    out[pix] = f;
    __shared__ float rmn[256], rmx[256];
    rmn[t] = f; rmx[t] = f; __syncthreads();
    for (int o = 128; o > 0; o >>= 1) {
        if (t < o) { rmn[t] = fminf(rmn[t], rmn[t + o]); rmx[t] = fmaxf(rmx[t], rmx[t + o]); }
        __syncthreads();
    }
    if (t == 0) {
        atomicMin(&minmax[0], __float_as_int(rmn[0]));
        atomicMax(&minmax[1], __float_as_int(rmx[0]));
    }
}

// -------- final normalize --------
__global__ void k_norm(float* __restrict__ out, const int* __restrict__ minmax) {
    float mn = __int_as_float(minmax[0]);
    float mx = __int_as_float(minmax[1]);
    int pix = blockIdx.x * 256 + threadIdx.x;
    if (mx != mn) out[pix] = (out[pix] - mn) / (mx - mn);
}

extern "C" void kernel_launch(void* const* d_in, const int* in_sizes, int n_in,
                              void* d_out, int out_size, void* d_ws, size_t ws_size,
                              hipStream_t stream) {
    const float* act = (const float*)d_in[0];
    const float* W1  = (const float*)d_in[1];
    const float* b1  = (const float*)d_in[2];
    const float* W2  = (const float*)d_in[3];
    const float* b2  = (const float*)d_in[4];
    const float* W3  = (const float*)d_in[5];
    const float* b3  = (const float*)d_in[6];
    float* out = (float*)d_out;
    float* ws = (float*)d_ws;

    k_maxpool<<<98, 256, 0, stream>>>(act, ws);
    k_phi<<<4096, 512, 0, stream>>>(W1, ws + WS_MP, ws + WS_DT);
    k_h1<<<4096, 64, 0, stream>>>(ws + WS_DT, b1, ws + WS_H1PRE, ws + WS_H1);
    k_gemv<FC, true><<<4096, 256, 0, stream>>>(W2, ws + WS_H1, b2, ws + WS_H2);
    k_gemv<FC, false><<<1000, 256, 0, stream>>>(W3, ws + WS_H2, b3, ws + WS_LOGITS);
    k_argmax<<<1, 256, 0, stream>>>(ws + WS_LOGITS, ws + WS_CLSBASE, out + 50176);
    k_gemm_abl<<<dim3(8, 64), 256, 0, stream>>>(ws + WS_DT, ws + WS_H1PRE, W2, b2, W3,
                                                ws + WS_CLSBASE, ws + WS_LOGPART);
    k_weighted<<<1, 256, 0, stream>>>(ws + WS_LOGPART, b3, ws + WS_CLSBASE, act,
                                      ws + WS_WEIGHTED);
    k_resize<<<196, 256, 0, stream>>>(ws + WS_WEIGHTED, out, (int*)(ws + WS_MINMAX));
    k_norm<<<196, 256, 0, stream>>>(out, (const int*)(ws + WS_MINMAX));
}

// Round 2
// 241.273 us; speedup vs baseline: 2.9309x; 2.9309x over previous
//
#include <hip/hip_runtime.h>
#include <math.h>

#define CCH 512
#define F1 25088      // 512*49
#define FC 4096
#define NCLS 1000
#define OW 224

// ws float offsets (shared by fast + fallback paths)
#define WS_DT 0                         // [4096][512] Dt[j][i]
#define WS_MP (WS_DT + FC*CCH)          // 25088
#define WS_H1PRE (WS_MP + F1)           // 4096
#define WS_H1 (WS_H1PRE + FC)           // 4096
#define WS_H2 (WS_H1 + FC)              // 4096
#define WS_LOGITS (WS_H2 + FC)          // 1000
#define WS_CLSBASE (WS_LOGITS + NCLS)   // 2: [0]=cls, [1]=base
#define WS_LOGPART (WS_CLSBASE + 2)     // [64][512]
#define WS_MINMAX (WS_LOGPART + 64*CCH) // 2 ints
#define WS_WEIGHTED (WS_MINMAX + 2)     // 196
#define WS_W2B (WS_WEIGHTED + 196)      // bf16 [4096][4096] -> 8388608 floats
#define WS_A (WS_W2B + FC*FC/2)         // bf16 [512][4096]  -> 1048576 floats
#define WS_END (WS_A + CCH*FC/2)
#define WS_NEED_BYTES ((size_t)WS_END * 4)

typedef __attribute__((ext_vector_type(8))) short bfrag;
typedef __attribute__((ext_vector_type(4))) float f32x4;

static __device__ __forceinline__ unsigned short f2bf(float x) {
    unsigned u = __float_as_uint(x);
    unsigned r = 0x7FFFu + ((u >> 16) & 1u);
    return (unsigned short)((u + r) >> 16);
}

#define GLD16(g, l) __builtin_amdgcn_global_load_lds( \
    (const __attribute__((address_space(1))) void*)(g), \
    (__attribute__((address_space(3))) void*)(l), 16, 0, 0)

// -------- maxpool 2x2 (+ init minmax) --------
__global__ void k_maxpool(const float* __restrict__ act, float* __restrict__ ws) {
    int t = threadIdx.x;
    if (blockIdx.x == 0) {
        if (t == 0) ((int*)(ws + WS_MINMAX))[0] = 0x7F800000; // +inf
        if (t == 1) ((int*)(ws + WS_MINMAX))[1] = 0;          // 0.0f
    }
    int idx = blockIdx.x * 256 + t;
    if (idx >= CCH * 49) return;
    int c = idx / 49, r = idx % 49, y = r / 7, x = r % 7;
    const float* a = act + c * 196 + (2 * y) * 14 + 2 * x;
    float m = fmaxf(fmaxf(a[0], a[1]), fmaxf(a[14], a[15]));
    ws[WS_MP + idx] = m;
}

// -------- layer-1 per-channel partials, coalesced via LDS product buffer --------
// Dt[j][i] = dot(W1[j, i*49 : i*49+49], mp[i*49 : ])
__global__ __launch_bounds__(256) void k_phi2(const float* __restrict__ W1,
                                              const float* __restrict__ mp,
                                              float* __restrict__ Dt) {
    __shared__ float buf[12544];  // 49KB: half of one W1 row's products
    int j = blockIdx.x, t = threadIdx.x;
    const float* row = W1 + (size_t)j * F1;
    #pragma unroll
    for (int h = 0; h < 2; ++h) {
        __syncthreads();  // protect buf reuse between halves
        const float4* src = (const float4*)(row + h * 12544);
        const float4* msc = (const float4*)(mp + h * 12544);
        for (int n = t; n < 3136; n += 256) {
            float4 w = src[n], m = msc[n];
            float4 p;
            p.x = w.x * m.x; p.y = w.y * m.y; p.z = w.z * m.z; p.w = w.w * m.w;
            *(float4*)&buf[n * 4] = p;
        }
        __syncthreads();
        const float* b = buf + t * 49;  // stride 49 coprime w/ 32 banks
        float s = 0.f;
        #pragma unroll
        for (int k = 0; k < 49; ++k) s += b[k];
        Dt[(size_t)j * CCH + h * 256 + t] = s;
    }
}

// -------- h1pre[j] = b1[j] + rowsum(Dt[j]); h1 = relu --------
__global__ void k_h1(const float* __restrict__ Dt, const float* __restrict__ b1,
                     float* __restrict__ h1pre, float* __restrict__ h1) {
    int j = blockIdx.x, t = threadIdx.x; // 64 threads
    const float* row = Dt + (size_t)j * CCH;
    float s = 0.f;
    for (int i = t; i < CCH; i += 64) s += row[i];
    for (int off = 32; off > 0; off >>= 1) s += __shfl_down(s, off, 64);
    if (t == 0) { float v = b1[j] + s; h1pre[j] = v; h1[j] = fmaxf(v, 0.f); }
}

// -------- K=4096 GEMV (vectorized), optional relu, optional bf16 dump of M --------
template <bool RELU, bool CVT>
__global__ void k_gemv4096(const float* __restrict__ M, const float* __restrict__ v,
                           const float* __restrict__ bias, float* __restrict__ out,
                           unsigned short* __restrict__ Mb) {
    int j = blockIdx.x, t = threadIdx.x; // 256 threads
    const float4* row = (const float4*)(M + (size_t)j * FC);
    const float4* vv = (const float4*)v;
    float s = 0.f;
    #pragma unroll
    for (int q = 0; q < 4; ++q) {
        int n = q * 256 + t;
        float4 w = row[n], x = vv[n];
        s += w.x * x.x + w.y * x.y + w.z * x.z + w.w * x.w;
        if (CVT) {
            ushort4 b;
            b.x = f2bf(w.x); b.y = f2bf(w.y); b.z = f2bf(w.z); b.w = f2bf(w.w);
            *(ushort4*)&Mb[(size_t)j * FC + n * 4] = b;
        }
    }
    __shared__ float red[256];
    red[t] = s; __syncthreads();
    if (t < 128) red[t] += red[t + 128]; __syncthreads();
    if (t < 64)  red[t] += red[t + 64];  __syncthreads();
    if (t < 64) {
        float x = red[t];
        for (int off = 32; off > 0; off >>= 1) x += __shfl_down(x, off, 64);
        if (t == 0) { float r = bias[j] + x; out[j] = RELU ? fmaxf(r, 0.f) : r; }
    }
}

// -------- argmax over logits (first max) --------
__global__ void k_argmax(const float* __restrict__ logits, float* __restrict__ clsbase,
                         float* __restrict__ dout_cls) {
    int t = threadIdx.x;
    float best = -INFINITY; int bi = NCLS;
    for (int n = t; n < NCLS; n += 256) {
        float v = logits[n];
        if (v > best || (v == best && n < bi)) { best = v; bi = n; }
    }
    __shared__ float bv[256]; __shared__ int bidx[256];
    bv[t] = best; bidx[t] = bi; __syncthreads();
    for (int o = 128; o > 0; o >>= 1) {
        if (t < o) {
            float v2 = bv[t + o]; int i2 = bidx[t + o];
            if (v2 > bv[t] || (v2 == bv[t] && i2 < bidx[t])) { bv[t] = v2; bidx[t] = i2; }
        }
        __syncthreads();
    }
    if (t == 0) { clsbase[0] = (float)bidx[0]; clsbase[1] = bv[0]; *dout_cls = (float)bidx[0]; }
}

// -------- A[i][k] = relu(h1pre[k] - Dt[k][i]) in bf16, [512][4096] layout --------
__global__ __launch_bounds__(256) void k_abuild(const float* __restrict__ Dt,
                                                const float* __restrict__ h1pre,
                                                unsigned short* __restrict__ A) {
    __shared__ unsigned short tile[64][72];
    int kt = blockIdx.x, it = blockIdx.y, t = threadIdx.x;
    int k0 = kt * 64, i0 = it * 64;
    #pragma unroll
    for (int q = 0; q < 16; ++q) {
        int kk = q * 4 + (t >> 6);
        int ii = t & 63;
        float v = fmaxf(h1pre[k0 + kk] - Dt[(size_t)(k0 + kk) * CCH + i0 + ii], 0.f);
        tile[kk][ii] = f2bf(v);
    }
    __syncthreads();
    #pragma unroll
    for (int q = 0; q < 4; ++q) {
        int c = q * 256 + t;           // 1024 chunks of 4 ushorts
        int ii = c >> 4, kc = c & 15;
        ushort4 v;
        v.x = tile[kc * 4 + 0][ii]; v.y = tile[kc * 4 + 1][ii];
        v.z = tile[kc * 4 + 2][ii]; v.w = tile[kc * 4 + 3][ii];
        *(ushort4*)&A[(size_t)(i0 + ii) * FC + k0 + kc * 4] = v;
    }
}

// -------- bf16 MFMA ablation GEMM + fused relu/b2/W3 reduction --------
// C[i][j] = sum_k A[i][k]*W2[j][k]; logit_part[nj][i] = sum_{j in tile} relu(C+b2[j])*W3[cls][j]
__global__ __launch_bounds__(256) void k_mfma_abl(
    const unsigned short* __restrict__ A, const unsigned short* __restrict__ W2b,
    const float* __restrict__ b2, const float* __restrict__ W3,
    const float* __restrict__ clsbase, float* __restrict__ logit_part) {
    __shared__ char lds[16384];        // As 8KB | Bs 8KB, 64 rows x 8 chunks x 16B
    int nj = blockIdx.x;               // 0..63 (XCD = nj%8: same-j i-blocks share L2)
    int mi = blockIdx.y;               // 0..7
    int t = threadIdx.x;
    int wid = t >> 6, lane = t & 63, lr = lane & 15, lh = lane >> 4;
    int i0 = mi * 64, j0 = nj * 64;

    const char* Ab = (const char*)(A + (size_t)i0 * FC);
    const char* Bb = (const char*)(W2b + (size_t)j0 * FC);
    char* As = lds;
    char* Bs = lds + 8192;

    // staging: LDS chunk c holds global (row=c>>3, koff=(c&7)^(row&7))
    int c0 = t, c1 = t + 256;
    int r0 = c0 >> 3, r1 = c1 >> 3;
    size_t goff0 = (size_t)r0 * 8192 + (size_t)(((c0 & 7) ^ (r0 & 7)) * 16);
    size_t goff1 = (size_t)r1 * 8192 + (size_t)(((c1 & 7) ^ (r1 & 7)) * 16);

    int arow = wid * 16 + lr;
    int aoff0 = arow * 128 + ((lh) ^ (arow & 7)) * 16;
    int aoff1 = arow * 128 + ((lh + 4) ^ (arow & 7)) * 16;

    f32x4 acc[4];
    #pragma unroll
    for (int jf = 0; jf < 4; ++jf) acc[jf] = (f32x4){0.f, 0.f, 0.f, 0.f};

    for (int kb = 0; kb < FC * 2; kb += 128) {   // 64 k-elems = 128B per step
        __syncthreads();
        GLD16(Ab + goff0 + kb, As + c0 * 16);
        GLD16(Ab + goff1 + kb, As + c1 * 16);
        GLD16(Bb + goff0 + kb, Bs + c0 * 16);
        GLD16(Bb + goff1 + kb, Bs + c1 * 16);
        __syncthreads();                          // compiler drains vmcnt before barrier
        bfrag a0 = *(const bfrag*)(As + aoff0);
        bfrag a1 = *(const bfrag*)(As + aoff1);
        #pragma unroll
        for (int jf = 0; jf < 4; ++jf) {
            int brow = jf * 16 + lr;
            bfrag b0 = *(const bfrag*)(Bs + brow * 128 + ((lh) ^ (brow & 7)) * 16);
            bfrag b1 = *(const bfrag*)(Bs + brow * 128 + ((lh + 4) ^ (brow & 7)) * 16);
            acc[jf] = __builtin_amdgcn_mfma_f32_16x16x32_bf16(a0, b0, acc[jf], 0, 0, 0);
            acc[jf] = __builtin_amdgcn_mfma_f32_16x16x32_bf16(a1, b1, acc[jf], 0, 0, 0);
        }
    }

    int cls = (int)clsbase[0];
    const float* w3r = W3 + (size_t)cls * FC;
    float part[4] = {0.f, 0.f, 0.f, 0.f};
    #pragma unroll
    for (int jf = 0; jf < 4; ++jf) {
        int j = j0 + jf * 16 + lr;
        float bb = b2[j], w3 = w3r[j];
        #pragma unroll
        for (int r = 0; r < 4; ++r)
            part[r] += fmaxf(acc[jf][r] + bb, 0.f) * w3;
    }
    #pragma unroll
    for (int r = 0; r < 4; ++r) {
        part[r] += __shfl_xor(part[r], 1, 64);
        part[r] += __shfl_xor(part[r], 2, 64);
        part[r] += __shfl_xor(part[r], 4, 64);
        part[r] += __shfl_xor(part[r], 8, 64);
    }
    if (lr == 0) {
        float4 v;
        v.x = part[0]; v.y = part[1]; v.z = part[2]; v.w = part[3];
        *(float4*)&logit_part[(size_t)nj * CCH + i0 + wid * 16 + lh * 4] = v;
    }
}

// -------- fallback fp32 ablation GEMM (used only if ws too small) --------
__global__ __launch_bounds__(256) void k_gemm_abl(
    const float* __restrict__ Dt, const float* __restrict__ h1pre,
    const float* __restrict__ W2, const float* __restrict__ b2,
    const float* __restrict__ W3, const float* __restrict__ clsbase,
    float* __restrict__ logit_part) {
    int mi = blockIdx.x, nj = blockIdx.y, t = threadIdx.x;
    int tx = t & 15, ty = t >> 4;
    int i0 = mi * 64, j0 = nj * 64;
    __shared__ float As[16][64];
    __shared__ float Bs[16][65];
    float acc[4][4] = {};
    for (int k0 = 0; k0 < FC; k0 += 16) {
        #pragma unroll
        for (int r = 0; r < 4; ++r) {
            int e = t + 256 * r; int kk = e >> 6, ii = e & 63;
            float hp = h1pre[k0 + kk];
            float d = Dt[(size_t)(k0 + kk) * CCH + i0 + ii];
            As[kk][ii] = fmaxf(hp - d, 0.f);
        }
        {
            int jj = t >> 2, kks = (t & 3) * 4;
            const float4 wv = *(const float4*)(W2 + (size_t)(j0 + jj) * FC + k0 + kks);
            Bs[kks + 0][jj] = wv.x; Bs[kks + 1][jj] = wv.y;
            Bs[kks + 2][jj] = wv.z; Bs[kks + 3][jj] = wv.w;
        }
        __syncthreads();
        #pragma unroll
        for (int kk = 0; kk < 16; ++kk) {
            float4 a4 = *(const float4*)&As[kk][tx * 4];
            float av[4] = {a4.x, a4.y, a4.z, a4.w};
            float bv[4] = {Bs[kk][ty * 4 + 0], Bs[kk][ty * 4 + 1],
                           Bs[kk][ty * 4 + 2], Bs[kk][ty * 4 + 3]};
            #pragma unroll
            for (int a = 0; a < 4; ++a)
                #pragma unroll
                for (int b = 0; b < 4; ++b)
                    acc[a][b] = fmaf(av[a], bv[b], acc[a][b]);
        }
        __syncthreads();
    }
    int cls = (int)clsbase[0];
    const float* w3r = W3 + (size_t)cls * FC;
    float part[4] = {0.f, 0.f, 0.f, 0.f};
    #pragma unroll
    for (int b = 0; b < 4; ++b) {
        int j2 = j0 + ty * 4 + b;
        float bb = b2[j2], w3 = w3r[j2];
        #pragma unroll
        for (int a = 0; a < 4; ++a) {
            float v = fmaxf(acc[a][b] + bb, 0.f);
            part[a] = fmaf(v, w3, part[a]);
        }
    }
    __shared__ float red[16][68];
    #pragma unroll
    for (int a = 0; a < 4; ++a) red[ty][tx * 4 + a] = part[a];
    __syncthreads();
    if (t < 64) {
        float s = 0.f;
        #pragma unroll
        for (int q = 0; q < 16; ++q) s += red[q][t];
        logit_part[nj * CCH + i0 + t] = s;
    }
}

// -------- alpha + weighted 14x14 map --------
__global__ void k_weighted(const float* __restrict__ logit_part, const float* __restrict__ b3,
                           const float* __restrict__ clsbase, const float* __restrict__ act,
                           float* __restrict__ weighted) {
    __shared__ float sA[CCH];
    int t = threadIdx.x;
    int cls = (int)clsbase[0]; float base = clsbase[1];
    float b3c = b3[cls];
    for (int i = t; i < CCH; i += 256) {
        float s = 0.f;
        for (int q = 0; q < 64; ++q) s += logit_part[q * CCH + i];
        float logit_i = s + b3c;
        sA[i] = (base - logit_i) / base;
    }
    __syncthreads();
    for (int p = t; p < 196; p += 256) {
        float s = 0.f;
        for (int i = 0; i < CCH; ++i) s = fmaf(sA[i], act[i * 196 + p], s);
        weighted[p] = s;
    }
}

// -------- bilinear 14->224 + relu + min/max --------
__global__ void k_resize(const float* __restrict__ weighted, float* __restrict__ out,
                         int* __restrict__ minmax) {
    __shared__ float sW[196];
    int t = threadIdx.x;
    if (t < 196) sW[t] = weighted[t];
    __syncthreads();
    int pix = blockIdx.x * 256 + t;
    int y = pix / OW, x = pix % OW;
    float uy = (y + 0.5f) * 0.0625f - 0.5f;
    float ux = (x + 0.5f) * 0.0625f - 0.5f;
    float y0f = floorf(uy), x0f = floorf(ux);
    float fy = uy - y0f, fx = ux - x0f;
    int y0 = (int)y0f, x0 = (int)x0f;
    int y0c = min(max(y0, 0), 13), y1c = min(max(y0 + 1, 0), 13);
    int x0c = min(max(x0, 0), 13), x1c = min(max(x0 + 1, 0), 13);
    float v00 = sW[y0c * 14 + x0c], v01 = sW[y0c * 14 + x1c];
    float v10 = sW[y1c * 14 + x0c], v11 = sW[y1c * 14 + x1c];
    float v0 = v00 + (v01 - v00) * fx;
    float v1 = v10 + (v11 - v10) * fx;
    float v = v0 + (v1 - v0) * fy;
    float f = fmaxf(v, 0.f);
    out[pix] = f;
    __shared__ float rmn[256], rmx[256];
    rmn[t] = f; rmx[t] = f; __syncthreads();
    for (int o = 128; o > 0; o >>= 1) {
        if (t < o) { rmn[t] = fminf(rmn[t], rmn[t + o]); rmx[t] = fmaxf(rmx[t], rmx[t + o]); }
        __syncthreads();
    }
    if (t == 0) {
        atomicMin(&minmax[0], __float_as_int(rmn[0]));
        atomicMax(&minmax[1], __float_as_int(rmx[0]));
    }
}

// -------- final normalize --------
__global__ void k_norm(float* __restrict__ out, const int* __restrict__ minmax) {
    float mn = __int_as_float(minmax[0]);
    float mx = __int_as_float(minmax[1]);
    int pix = blockIdx.x * 256 + threadIdx.x;
    if (mx != mn) out[pix] = (out[pix] - mn) / (mx - mn);
}

extern "C" void kernel_launch(void* const* d_in, const int* in_sizes, int n_in,
                              void* d_out, int out_size, void* d_ws, size_t ws_size,
                              hipStream_t stream) {
    const float* act = (const float*)d_in[0];
    const float* W1  = (const float*)d_in[1];
    const float* b1  = (const float*)d_in[2];
    const float* W2  = (const float*)d_in[3];
    const float* b2  = (const float*)d_in[4];
    const float* W3  = (const float*)d_in[5];
    const float* b3  = (const float*)d_in[6];
    float* out = (float*)d_out;
    float* ws = (float*)d_ws;
    const bool fast = (ws_size >= WS_NEED_BYTES);

    k_maxpool<<<98, 256, 0, stream>>>(act, ws);
    k_phi2<<<4096, 256, 0, stream>>>(W1, ws + WS_MP, ws + WS_DT);
    k_h1<<<4096, 64, 0, stream>>>(ws + WS_DT, b1, ws + WS_H1PRE, ws + WS_H1);
    if (fast) {
        k_gemv4096<true, true><<<4096, 256, 0, stream>>>(
            W2, ws + WS_H1, b2, ws + WS_H2, (unsigned short*)(ws + WS_W2B));
    } else {
        k_gemv4096<true, false><<<4096, 256, 0, stream>>>(
            W2, ws + WS_H1, b2, ws + WS_H2, nullptr);
    }
    k_gemv4096<false, false><<<1000, 256, 0, stream>>>(W3, ws + WS_H2, b3,
                                                       ws + WS_LOGITS, nullptr);
    k_argmax<<<1, 256, 0, stream>>>(ws + WS_LOGITS, ws + WS_CLSBASE, out + 50176);
    if (fast) {
        k_abuild<<<dim3(64, 8), 256, 0, stream>>>(ws + WS_DT, ws + WS_H1PRE,
                                                  (unsigned short*)(ws + WS_A));
        k_mfma_abl<<<dim3(64, 8), 256, 0, stream>>>(
            (const unsigned short*)(ws + WS_A), (const unsigned short*)(ws + WS_W2B),
            b2, W3, ws + WS_CLSBASE, ws + WS_LOGPART);
    } else {
        k_gemm_abl<<<dim3(8, 64), 256, 0, stream>>>(ws + WS_DT, ws + WS_H1PRE, W2, b2, W3,
                                                    ws + WS_CLSBASE, ws + WS_LOGPART);
    }
    k_weighted<<<1, 256, 0, stream>>>(ws + WS_LOGPART, b3, ws + WS_CLSBASE, act,
                                      ws + WS_WEIGHTED);
    k_resize<<<196, 256, 0, stream>>>(ws + WS_WEIGHTED, out, (int*)(ws + WS_MINMAX));
    k_norm<<<196, 256, 0, stream>>>(out, (const int*)(ws + WS_MINMAX));
}

// Round 3
// 219.143 us; speedup vs baseline: 3.2269x; 1.1010x over previous
//
#include <hip/hip_runtime.h>
#include <math.h>

#define CCH 512
#define F1 25088      // 512*49
#define FC 4096
#define NCLS 1000
#define OW 224
#define KSPLIT 4
#define KSLICE 1024   // FC/KSPLIT
#define PSTRIDE (CCH*FC)   // one k-partial plane (elems)

// ws float offsets
#define WS_DT 0                         // [4096][512] Dt[j][i]
#define WS_MP (WS_DT + FC*CCH)          // 25088
#define WS_QS (WS_MP + F1)              // [4096][4] quarter sums
#define WS_H1PRE (WS_QS + FC*4)         // 4096
#define WS_H1 (WS_H1PRE + FC)           // 4096
#define WS_H2 (WS_H1 + FC)              // 4096
#define WS_LOGITS (WS_H2 + FC)          // 1000
#define WS_CLSBASE (WS_LOGITS + NCLS)   // 2
#define WS_ALPHA (WS_CLSBASE + 2)       // 512
#define WS_MINMAX (WS_ALPHA + CCH)      // 2 ints
#define WS_WEIGHTED (WS_MINMAX + 2)     // 196
#define WS_LOGPART (WS_WEIGHTED + 196)  // [64][512] (fallback path)
#define WS_A (WS_LOGPART + 64*CCH)      // bf16 [512][4096] -> 1048576 floats
#define WS_PART (WS_A + CCH*FC/2)       // f32 [4][512][4096]
#define WS_END (WS_PART + KSPLIT*CCH*FC)
#define WS_NEED_BYTES ((size_t)WS_END * 4)

typedef __attribute__((ext_vector_type(8))) short bfrag;
typedef __attribute__((ext_vector_type(4))) float f32x4;

static __device__ __forceinline__ unsigned short f2bf(float x) {
    unsigned u = __float_as_uint(x);
    unsigned r = 0x7FFFu + ((u >> 16) & 1u);
    return (unsigned short)((u + r) >> 16);
}

#define GLD16(g, l) __builtin_amdgcn_global_load_lds( \
    (const __attribute__((address_space(1))) void*)(g), \
    (__attribute__((address_space(3))) void*)(l), 16, 0, 0)

// -------- maxpool 2x2 (+ init minmax) --------
__global__ void k_maxpool(const float* __restrict__ act, float* __restrict__ ws) {
    int t = threadIdx.x;
    if (blockIdx.x == 0) {
        if (t == 0) ((int*)(ws + WS_MINMAX))[0] = 0x7F800000;
        if (t == 1) ((int*)(ws + WS_MINMAX))[1] = 0;
    }
    int idx = blockIdx.x * 256 + t;
    if (idx >= CCH * 49) return;
    int c = idx / 49, r = idx % 49, y = r / 7, x = r % 7;
    const float* a = act + c * 196 + (2 * y) * 14 + 2 * x;
    float m = fmaxf(fmaxf(a[0], a[1]), fmaxf(a[14], a[15]));
    ws[WS_MP + idx] = m;
}

// -------- layer-1 partials, quarter-row blocks (6 blocks/CU for MLP) --------
// block b: j = b>>2, quarter q = b&3 (128 channels). Writes Dt + quarter-sum qs.
__global__ __launch_bounds__(256) void k_phi3(const float* __restrict__ W1,
                                              const float* __restrict__ mp,
                                              float* __restrict__ Dt,
                                              float* __restrict__ qs) {
    __shared__ float buf[6272];   // 24.5KB products
    __shared__ float red[128];
    int b = blockIdx.x;           // 0..16383
    int j = b >> 2, q = b & 3;
    int t = threadIdx.x;
    const float4* src = (const float4*)(W1 + (size_t)j * F1 + q * 6272);
    const float4* msc = (const float4*)(mp + q * 6272);
    for (int n = t; n < 1568; n += 256) {
        float4 w = src[n], m = msc[n];
        float4 p;
        p.x = w.x * m.x; p.y = w.y * m.y; p.z = w.z * m.z; p.w = w.w * m.w;
        *(float4*)&buf[n * 4] = p;
    }
    __syncthreads();
    if (t < 128) {
        const float* bb = buf + t * 49;   // stride 49: 2-way bank alias (free)
        float s = 0.f;
        #pragma unroll
        for (int k = 0; k < 49; ++k) s += bb[k];
        Dt[(size_t)j * CCH + q * 128 + t] = s;
        red[t] = s;
    }
    __syncthreads();
    if (t < 64) {
        float v = red[t] + red[t + 64];
        for (int off = 32; off > 0; off >>= 1) v += __shfl_down(v, off, 64);
        if (t == 0) qs[b] = v;
    }
}

// -------- h1pre from quarter sums --------
__global__ void k_h1b(const float* __restrict__ qs, const float* __restrict__ b1,
                      float* __restrict__ h1pre, float* __restrict__ h1) {
    int j = blockIdx.x * 256 + threadIdx.x;
    if (j < FC) {
        const float* g = qs + j * 4;
        float v = b1[j] + ((g[0] + g[1]) + (g[2] + g[3]));
        h1pre[j] = v; h1[j] = fmaxf(v, 0.f);
    }
}

// -------- K=4096 GEMV (vectorized) --------
template <bool RELU>
__global__ void k_gemv4096(const float* __restrict__ M, const float* __restrict__ v,
                           const float* __restrict__ bias, float* __restrict__ out) {
    int j = blockIdx.x, t = threadIdx.x;
    const float4* row = (const float4*)(M + (size_t)j * FC);
    const float4* vv = (const float4*)v;
    float s = 0.f;
    #pragma unroll
    for (int q = 0; q < 4; ++q) {
        int n = q * 256 + t;
        float4 w = row[n], x = vv[n];
        s += w.x * x.x + w.y * x.y + w.z * x.z + w.w * x.w;
    }
    __shared__ float red[256];
    red[t] = s; __syncthreads();
    if (t < 128) red[t] += red[t + 128]; __syncthreads();
    if (t < 64)  red[t] += red[t + 64];  __syncthreads();
    if (t < 64) {
        float x = red[t];
        for (int off = 32; off > 0; off >>= 1) x += __shfl_down(x, off, 64);
        if (t == 0) { float r = bias[j] + x; out[j] = RELU ? fmaxf(r, 0.f) : r; }
    }
}

// -------- argmax over logits --------
__global__ void k_argmax(const float* __restrict__ logits, float* __restrict__ clsbase,
                         float* __restrict__ dout_cls) {
    int t = threadIdx.x;
    float best = -INFINITY; int bi = NCLS;
    for (int n = t; n < NCLS; n += 256) {
        float v = logits[n];
        if (v > best || (v == best && n < bi)) { best = v; bi = n; }
    }
    __shared__ float bv[256]; __shared__ int bidx[256];
    bv[t] = best; bidx[t] = bi; __syncthreads();
    for (int o = 128; o > 0; o >>= 1) {
        if (t < o) {
            float v2 = bv[t + o]; int i2 = bidx[t + o];
            if (v2 > bv[t] || (v2 == bv[t] && i2 < bidx[t])) { bv[t] = v2; bidx[t] = i2; }
        }
        __syncthreads();
    }
    if (t == 0) { clsbase[0] = (float)bidx[0]; clsbase[1] = bv[0]; *dout_cls = (float)bidx[0]; }
}

// -------- A[i][k] = relu(h1pre[k] - Dt[k][i]) in bf16, [512][4096] --------
__global__ __launch_bounds__(256) void k_abuild(const float* __restrict__ Dt,
                                                const float* __restrict__ h1pre,
                                                unsigned short* __restrict__ A) {
    __shared__ unsigned short tile[64][72];
    int kt = blockIdx.x, it = blockIdx.y, t = threadIdx.x;
    int k0 = kt * 64, i0 = it * 64;
    #pragma unroll
    for (int q = 0; q < 16; ++q) {
        int kk = q * 4 + (t >> 6);
        int ii = t & 63;
        float v = fmaxf(h1pre[k0 + kk] - Dt[(size_t)(k0 + kk) * CCH + i0 + ii], 0.f);
        tile[kk][ii] = f2bf(v);
    }
    __syncthreads();
    #pragma unroll
    for (int q = 0; q < 4; ++q) {
        int c = q * 256 + t;
        int ii = c >> 4, kc = c & 15;
        ushort4 v;
        v.x = tile[kc * 4 + 0][ii]; v.y = tile[kc * 4 + 1][ii];
        v.z = tile[kc * 4 + 2][ii]; v.w = tile[kc * 4 + 3][ii];
        *(ushort4*)&A[(size_t)(i0 + ii) * FC + k0 + kc * 4] = v;
    }
}

// -------- fused ablation GEMM: reads W2 fp32 ONCE, converts in-register --------
// grid (64 j-tiles, 4 k-splits) x 512 thr. part[ks][m][j] = sum_{k in slice} A[m][k]*W2[j][k]
__global__ __launch_bounds__(512) void k_mfma_all(
    const unsigned short* __restrict__ A, const float* __restrict__ W2,
    float* __restrict__ part) {
    __shared__ char As[65536];   // 512 rows x 8 chunks x 16B
    __shared__ char Bs[8192];    // 64 rows x 8 chunks x 16B
    int nj = blockIdx.x;         // 0..63
    int ks = blockIdx.y;         // 0..3
    int t = threadIdx.x;
    int wid = t >> 6, lane = t & 63, lr = lane & 15, lh = lane >> 4;
    int j0 = nj * 64;

    // W2 fp32 source for this thread: row j0+(t>>3), chunk (t&7) (8 floats)
    int wrow = t >> 3, wch = t & 7;
    const float* wsrc = W2 + (size_t)(j0 + wrow) * FC + (size_t)ks * KSLICE + wch * 8;
    // B LDS dest (swizzled): LDS[row][wch ^ (row&7)]
    char* bdst = Bs + ((size_t)wrow * 8 + (wch ^ (wrow & 7))) * 16;

    f32x4 acc[4][4];
    #pragma unroll
    for (int f = 0; f < 4; ++f)
        #pragma unroll
        for (int n = 0; n < 4; ++n) acc[f][n] = (f32x4){0.f, 0.f, 0.f, 0.f};

    for (int kst = 0; kst < KSLICE; kst += 64) {
        size_t k0 = (size_t)ks * KSLICE + kst;
        __syncthreads();   // previous MFMA phase done reading LDS
        // stage A: 4096 chunks, pre-swizzled global source, linear LDS dest
        #pragma unroll
        for (int r = 0; r < 8; ++r) {
            int c = t + 512 * r;
            int row = c >> 3, ch = c & 7;
            size_t g = (size_t)row * FC + k0 + (size_t)((ch ^ (row & 7)) * 8);
            GLD16(A + g, As + (size_t)c * 16);
        }
        // stage B: load 8 fp32, convert, swizzled ds_write_b128
        {
            const float4 wa = ((const float4*)(wsrc + kst))[0];
            const float4 wb = ((const float4*)(wsrc + kst))[1];
            union { bfrag v; unsigned short u[8]; } pk;
            pk.u[0] = f2bf(wa.x); pk.u[1] = f2bf(wa.y);
            pk.u[2] = f2bf(wa.z); pk.u[3] = f2bf(wa.w);
            pk.u[4] = f2bf(wb.x); pk.u[5] = f2bf(wb.y);
            pk.u[6] = f2bf(wb.z); pk.u[7] = f2bf(wb.w);
            *(bfrag*)bdst = pk.v;
        }
        __syncthreads();   // drains vmcnt (gld_lds) + lgkm (ds_write)
        #pragma unroll
        for (int kf = 0; kf < 2; ++kf) {
            bfrag bfr[4];
            #pragma unroll
            for (int n = 0; n < 4; ++n) {
                int brow = n * 16 + lr;
                bfr[n] = *(const bfrag*)(Bs + ((size_t)brow * 8 + ((kf * 4 + lh) ^ (brow & 7))) * 16);
            }
            #pragma unroll
            for (int f = 0; f < 4; ++f) {
                int arow = wid * 64 + f * 16 + lr;
                bfrag af = *(const bfrag*)(As + ((size_t)arow * 8 + ((kf * 4 + lh) ^ (arow & 7))) * 16);
                #pragma unroll
                for (int n = 0; n < 4; ++n)
                    acc[f][n] = __builtin_amdgcn_mfma_f32_16x16x32_bf16(af, bfr[n], acc[f][n], 0, 0, 0);
            }
        }
    }
    // write partials: row = wid*64 + f*16 + lh*4 + r, col = j0 + n*16 + lr
    float* base = part + (size_t)ks * PSTRIDE;
    #pragma unroll
    for (int f = 0; f < 4; ++f) {
        #pragma unroll
        for (int n = 0; n < 4; ++n) {
            #pragma unroll
            for (int r = 0; r < 4; ++r) {
                int row = wid * 64 + f * 16 + lh * 4 + r;
                base[(size_t)row * FC + j0 + n * 16 + lr] = acc[f][n][r];
            }
        }
    }
}

// -------- per-ablation class logit from k-partials + alpha --------
__global__ __launch_bounds__(256) void k_alpha(
    const float* __restrict__ part, const float* __restrict__ b2,
    const float* __restrict__ W3, const float* __restrict__ b3,
    const float* __restrict__ clsbase, float* __restrict__ alpha) {
    int i = blockIdx.x, t = threadIdx.x;
    int cls = (int)clsbase[0]; float base = clsbase[1];
    const float* w3r = W3 + (size_t)cls * FC;
    const float* p0 = part + (size_t)i * FC;
    float s = 0.f;
    for (int j = t; j < FC; j += 256) {
        float v = ((p0[j] + p0[j + PSTRIDE]) + (p0[j + 2 * PSTRIDE] + p0[j + 3 * PSTRIDE]))
                  + b2[j];
        s += fmaxf(v, 0.f) * w3r[j];
    }
    __shared__ float red[256];
    red[t] = s; __syncthreads();
    if (t < 128) red[t] += red[t + 128]; __syncthreads();
    if (t < 64)  red[t] += red[t + 64];  __syncthreads();
    if (t < 64) {
        float x = red[t];
        for (int off = 32; off > 0; off >>= 1) x += __shfl_down(x, off, 64);
        if (t == 0) {
            float logit = x + b3[cls];
            alpha[i] = (base - logit) / base;
        }
    }
}

// -------- weighted 14x14 map from alpha --------
__global__ void k_weighted2(const float* __restrict__ alpha, const float* __restrict__ act,
                            float* __restrict__ weighted) {
    __shared__ float sA[CCH];
    int t = threadIdx.x;
    for (int i = t; i < CCH; i += 256) sA[i] = alpha[i];
    __syncthreads();
    for (int p = t; p < 196; p += 256) {
        float s = 0.f;
        for (int i = 0; i < CCH; ++i) s = fmaf(sA[i], act[i * 196 + p], s);
        weighted[p] = s;
    }
}

// ======== fallback fp32 path kernels (ws too small) ========
__global__ __launch_bounds__(256) void k_gemm_abl(
    const float* __restrict__ Dt, const float* __restrict__ h1pre,
    const float* __restrict__ W2, const float* __restrict__ b2,
    const float* __restrict__ W3, const float* __restrict__ clsbase,
    float* __restrict__ logit_part) {
    int mi = blockIdx.x, nj = blockIdx.y, t = threadIdx.x;
    int tx = t & 15, ty = t >> 4;
    int i0 = mi * 64, j0 = nj * 64;
    __shared__ float As2[16][64];
    __shared__ float Bs2[16][65];
    float acc[4][4] = {};
    for (int k0 = 0; k0 < FC; k0 += 16) {
        #pragma unroll
        for (int r = 0; r < 4; ++r) {
            int e = t + 256 * r; int kk = e >> 6, ii = e & 63;
            As2[kk][ii] = fmaxf(h1pre[k0 + kk] - Dt[(size_t)(k0 + kk) * CCH + i0 + ii], 0.f);
        }
        {
            int jj = t >> 2, kks = (t & 3) * 4;
            const float4 wv = *(const float4*)(W2 + (size_t)(j0 + jj) * FC + k0 + kks);
            Bs2[kks + 0][jj] = wv.x; Bs2[kks + 1][jj] = wv.y;
            Bs2[kks + 2][jj] = wv.z; Bs2[kks + 3][jj] = wv.w;
        }
        __syncthreads();
        #pragma unroll
        for (int kk = 0; kk < 16; ++kk) {
            float4 a4 = *(const float4*)&As2[kk][tx * 4];
            float av[4] = {a4.x, a4.y, a4.z, a4.w};
            float bv[4] = {Bs2[kk][ty * 4 + 0], Bs2[kk][ty * 4 + 1],
                           Bs2[kk][ty * 4 + 2], Bs2[kk][ty * 4 + 3]};
            #pragma unroll
            for (int a = 0; a < 4; ++a)
                #pragma unroll
                for (int b = 0; b < 4; ++b)
                    acc[a][b] = fmaf(av[a], bv[b], acc[a][b]);
        }
        __syncthreads();
    }
    int cls = (int)clsbase[0];
    const float* w3r = W3 + (size_t)cls * FC;
    float prt[4] = {0.f, 0.f, 0.f, 0.f};
    #pragma unroll
    for (int b = 0; b < 4; ++b) {
        int j2 = j0 + ty * 4 + b;
        float bb = b2[j2], w3 = w3r[j2];
        #pragma unroll
        for (int a = 0; a < 4; ++a) prt[a] = fmaf(fmaxf(acc[a][b] + bb, 0.f), w3, prt[a]);
    }
    __shared__ float red2[16][68];
    #pragma unroll
    for (int a = 0; a < 4; ++a) red2[ty][tx * 4 + a] = prt[a];
    __syncthreads();
    if (t < 64) {
        float s = 0.f;
        #pragma unroll
        for (int q = 0; q < 16; ++q) s += red2[q][t];
        logit_part[nj * CCH + i0 + t] = s;
    }
}

__global__ void k_alpha_fb(const float* __restrict__ logit_part, const float* __restrict__ b3,
                           const float* __restrict__ clsbase, float* __restrict__ alpha) {
    int t = blockIdx.x * 256 + threadIdx.x;
    if (t >= CCH) return;
    int cls = (int)clsbase[0]; float base = clsbase[1];
    float s = 0.f;
    for (int q = 0; q < 64; ++q) s += logit_part[q * CCH + t];
    alpha[t] = (base - (s + b3[cls])) / base;
}

// -------- bilinear 14->224 + relu + min/max --------
__global__ void k_resize(const float* __restrict__ weighted, float* __restrict__ out,
                         int* __restrict__ minmax) {
    __shared__ float sW[196];
    int t = threadIdx.x;
    if (t < 196) sW[t] = weighted[t];
    __syncthreads();
    int pix = blockIdx.x * 256 + t;
    int y = pix / OW, x = pix % OW;
    float uy = (y + 0.5f) * 0.0625f - 0.5f;
    float ux = (x + 0.5f) * 0.0625f - 0.5f;
    float y0f = floorf(uy), x0f = floorf(ux);
    float fy = uy - y0f, fx = ux - x0f;
    int y0 = (int)y0f, x0 = (int)x0f;
    int y0c = min(max(y0, 0), 13), y1c = min(max(y0 + 1, 0), 13);
    int x0c = min(max(x0, 0), 13), x1c = min(max(x0 + 1, 0), 13);
    float v00 = sW[y0c * 14 + x0c], v01 = sW[y0c * 14 + x1c];
    float v10 = sW[y1c * 14 + x0c], v11 = sW[y1c * 14 + x1c];
    float v0 = v00 + (v01 - v00) * fx;
    float v1 = v10 + (v11 - v10) * fx;
    float v = v0 + (v1 - v0) * fy;
    float f = fmaxf(v, 0.f);
    out[pix] = f;
    __shared__ float rmn[256], rmx[256];
    rmn[t] = f; rmx[t] = f; __syncthreads();
    for (int o = 128; o > 0; o >>= 1) {
        if (t < o) { rmn[t] = fminf(rmn[t], rmn[t + o]); rmx[t] = fmaxf(rmx[t], rmx[t + o]); }
        __syncthreads();
    }
    if (t == 0) {
        atomicMin(&minmax[0], __float_as_int(rmn[0]));
        atomicMax(&minmax[1], __float_as_int(rmx[0]));
    }
}

__global__ void k_norm(float* __restrict__ out, const int* __restrict__ minmax) {
    float mn = __int_as_float(minmax[0]);
    float mx = __int_as_float(minmax[1]);
    int pix = blockIdx.x * 256 + threadIdx.x;
    if (mx != mn) out[pix] = (out[pix] - mn) / (mx - mn);
}

extern "C" void kernel_launch(void* const* d_in, const int* in_sizes, int n_in,
                              void* d_out, int out_size, void* d_ws, size_t ws_size,
                              hipStream_t stream) {
    const float* act = (const float*)d_in[0];
    const float* W1  = (const float*)d_in[1];
    const float* b1  = (const float*)d_in[2];
    const float* W2  = (const float*)d_in[3];
    const float* b2  = (const float*)d_in[4];
    const float* W3  = (const float*)d_in[5];
    const float* b3  = (const float*)d_in[6];
    float* out = (float*)d_out;
    float* ws = (float*)d_ws;
    const bool fast = (ws_size >= WS_NEED_BYTES);

    k_maxpool<<<98, 256, 0, stream>>>(act, ws);
    k_phi3<<<16384, 256, 0, stream>>>(W1, ws + WS_MP, ws + WS_DT, ws + WS_QS);
    k_h1b<<<16, 256, 0, stream>>>(ws + WS_QS, b1, ws + WS_H1PRE, ws + WS_H1);
    // base pass in full fp32 (argmax must be exact)
    k_gemv4096<true><<<4096, 256, 0, stream>>>(W2, ws + WS_H1, b2, ws + WS_H2);
    k_gemv4096<false><<<1000, 256, 0, stream>>>(W3, ws + WS_H2, b3, ws + WS_LOGITS);
    k_argmax<<<1, 256, 0, stream>>>(ws + WS_LOGITS, ws + WS_CLSBASE, out + 50176);
    if (fast) {
        k_abuild<<<dim3(64, 8), 256, 0, stream>>>(ws + WS_DT, ws + WS_H1PRE,
                                                  (unsigned short*)(ws + WS_A));
        k_mfma_all<<<dim3(64, KSPLIT), 512, 0, stream>>>(
            (const unsigned short*)(ws + WS_A), W2, ws + WS_PART);
        k_alpha<<<CCH, 256, 0, stream>>>(ws + WS_PART, b2, W3, b3,
                                         ws + WS_CLSBASE, ws + WS_ALPHA);
    } else {
        k_gemm_abl<<<dim3(8, 64), 256, 0, stream>>>(ws + WS_DT, ws + WS_H1PRE, W2, b2, W3,
                                                    ws + WS_CLSBASE, ws + WS_LOGPART);
        k_alpha_fb<<<2, 256, 0, stream>>>(ws + WS_LOGPART, b3, ws + WS_CLSBASE,
                                          ws + WS_ALPHA);
    }
    k_weighted2<<<1, 256, 0, stream>>>(ws + WS_ALPHA, act, ws + WS_WEIGHTED);
    k_resize<<<196, 256, 0, stream>>>(ws + WS_WEIGHTED, out, (int*)(ws + WS_MINMAX));
    k_norm<<<196, 256, 0, stream>>>(out, (const int*)(ws + WS_MINMAX));
}